// Round 3
// baseline (1410.264 us; speedup 1.0000x reference)
//
#include <hip/hip_runtime.h>
#include <hip/hip_bf16.h>
#include <math.h>

#define LEAKY 0.2f

__device__ __forceinline__ void atomicMaxFloat(float* addr, float v) {
    if (__float_as_int(v) >= 0) atomicMax((int*)addr, __float_as_int(v));
    else                        atomicMin((unsigned int*)addr, __float_as_uint(v));
}

// ---------------- generic fp32 tiled GEMM: C[M,NC] = A[M,K] @ B[K,NC] ----------------
#define BM 64
#define BN 64
#define BK 32
__global__ __launch_bounds__(256) void gemm_f32(const float* __restrict__ A,
                                                const float* __restrict__ B,
                                                float* __restrict__ C,
                                                int M, int K, int NC) {
    __shared__ float As[BK][BM + 1];   // +1 pad: conflict-free transposed store
    __shared__ float Bs[BK][BN];
    const int tid = threadIdx.x;
    const int bm = blockIdx.x * BM;
    const int bn = blockIdx.y * BN;
    const int tx = tid & 15, ty = tid >> 4;
    float acc[4][4] = {};
    for (int k0 = 0; k0 < K; k0 += BK) {
        #pragma unroll
        for (int i = 0; i < (BM * BK) / 256; ++i) {
            int idx = tid + i * 256;
            int r = idx >> 5, c = idx & 31;            // BK = 32
            int gr = bm + r;
            As[c][r] = (gr < M) ? A[gr * K + k0 + c] : 0.f;
        }
        #pragma unroll
        for (int i = 0; i < (BK * BN) / 256; ++i) {
            int idx = tid + i * 256;
            int r = idx >> 6, c = idx & 63;            // BN = 64
            Bs[r][c] = B[(k0 + r) * NC + bn + c];
        }
        __syncthreads();
        #pragma unroll
        for (int k = 0; k < BK; ++k) {
            float a[4], b[4];
            #pragma unroll
            for (int i = 0; i < 4; ++i) a[i] = As[k][ty * 4 + i];
            #pragma unroll
            for (int j = 0; j < 4; ++j) b[j] = Bs[k][tx * 4 + j];
            #pragma unroll
            for (int i = 0; i < 4; ++i)
                #pragma unroll
                for (int j = 0; j < 4; ++j)
                    acc[i][j] += a[i] * b[j];
        }
        __syncthreads();
    }
    #pragma unroll
    for (int i = 0; i < 4; ++i) {
        int gr = bm + ty * 4 + i;
        if (gr < M) {
            #pragma unroll
            for (int j = 0; j < 4; ++j)
                C[gr * NC + bn + tx * 4 + j] = acc[i][j];
        }
    }
}

// ---------------- attention scores: asrc[n,h] = sum_c h[n,h,c]*att_src[h,c] ----------------
// block 256; each 64-lane wave covers exactly one (node, head) group (HC in {64,256}).
__global__ __launch_bounds__(256) void attn_scores(const float* __restrict__ h,
                                                   const float* __restrict__ att_s,
                                                   const float* __restrict__ att_d,
                                                   float* __restrict__ asrc,
                                                   float* __restrict__ adst,
                                                   int nN, int HC) {
    int idx = blockIdx.x * 256 + threadIdx.x;
    int lane = threadIdx.x & 63;
    int n = idx / HC;
    int w = idx - n * HC;            // = head*64 + lane
    if (n >= nN) return;
    float hv = h[n * HC + w];
    float vs = hv * att_s[w];
    float vd = hv * att_d[w];
    #pragma unroll
    for (int off = 32; off > 0; off >>= 1) {
        vs += __shfl_down(vs, off);
        vd += __shfl_down(vd, off);
    }
    if (lane == 0) {
        int head = w >> 6;
        int H = HC >> 6;
        asrc[n * H + head] = vs;
        adst[n * H + head] = vd;
    }
}

// ---------------- fill ----------------
__global__ void fill_val(float* __restrict__ p, int n, float v) {
    int i = blockIdx.x * 256 + threadIdx.x;
    if (i < n) p[i] = v;
}

// ---------------- layer-1 edge kernels (4 heads) ----------------
__global__ __launch_bounds__(256) void edge_max1(const int* __restrict__ ei, int E_, int N_,
                                                 const float* __restrict__ asrc,
                                                 const float* __restrict__ adst,
                                                 float* __restrict__ m) {
    int eid = blockIdx.x * 256 + threadIdx.x;
    int Etot = E_ + N_;
    if (eid >= Etot) return;
    int src, dst;
    if (eid < E_) { src = ei[eid]; dst = ei[E_ + eid]; }
    else          { src = dst = eid - E_; }
    float4 as = *(const float4*)(asrc + src * 4);
    float4 ad = *(const float4*)(adst + dst * 4);
    float e0 = as.x + ad.x; e0 = e0 > 0.f ? e0 : LEAKY * e0;
    float e1 = as.y + ad.y; e1 = e1 > 0.f ? e1 : LEAKY * e1;
    float e2 = as.z + ad.z; e2 = e2 > 0.f ? e2 : LEAKY * e2;
    float e3 = as.w + ad.w; e3 = e3 > 0.f ? e3 : LEAKY * e3;
    atomicMaxFloat(&m[dst * 4 + 0], e0);
    atomicMaxFloat(&m[dst * 4 + 1], e1);
    atomicMaxFloat(&m[dst * 4 + 2], e2);
    atomicMaxFloat(&m[dst * 4 + 3], e3);
}

// wave per edge: lane l handles channel h*64+l for h=0..3
__global__ __launch_bounds__(256) void edge_accum1(const int* __restrict__ ei, int E_, int N_,
                                                   const float* __restrict__ asrc,
                                                   const float* __restrict__ adst,
                                                   const float* __restrict__ m,
                                                   float* __restrict__ den,
                                                   const float* __restrict__ h1,
                                                   float* __restrict__ acc) {
    int wave = threadIdx.x >> 6;
    int lane = threadIdx.x & 63;
    int eid = blockIdx.x * 4 + wave;
    int Etot = E_ + N_;
    if (eid >= Etot) return;
    int src, dst;
    if (eid < E_) { src = ei[eid]; dst = ei[E_ + eid]; }
    else          { src = dst = eid - E_; }
    float4 as = *(const float4*)(asrc + src * 4);
    float4 ad = *(const float4*)(adst + dst * 4);
    float4 mm = *(const float4*)(m + dst * 4);
    float w0, w1, w2, w3;
    { float e = as.x + ad.x; e = e > 0.f ? e : LEAKY * e; w0 = __expf(e - mm.x); }
    { float e = as.y + ad.y; e = e > 0.f ? e : LEAKY * e; w1 = __expf(e - mm.y); }
    { float e = as.z + ad.z; e = e > 0.f ? e : LEAKY * e; w2 = __expf(e - mm.z); }
    { float e = as.w + ad.w; e = e > 0.f ? e : LEAKY * e; w3 = __expf(e - mm.w); }
    if (lane < 4) {
        float wl = lane == 0 ? w0 : lane == 1 ? w1 : lane == 2 ? w2 : w3;
        atomicAdd(&den[dst * 4 + lane], wl);
    }
    int sbase = src * 256 + lane;
    int dbase = dst * 256 + lane;
    atomicAdd(&acc[dbase +   0], w0 * h1[sbase +   0]);
    atomicAdd(&acc[dbase +  64], w1 * h1[sbase +  64]);
    atomicAdd(&acc[dbase + 128], w2 * h1[sbase + 128]);
    atomicAdd(&acc[dbase + 192], w3 * h1[sbase + 192]);
}

// ---------------- layer-2 edge kernels (1 head) ----------------
__global__ __launch_bounds__(256) void edge_max2(const int* __restrict__ ei, int E_, int N_,
                                                 const float* __restrict__ asrc,
                                                 const float* __restrict__ adst,
                                                 float* __restrict__ m) {
    int eid = blockIdx.x * 256 + threadIdx.x;
    int Etot = E_ + N_;
    if (eid >= Etot) return;
    int src, dst;
    if (eid < E_) { src = ei[eid]; dst = ei[E_ + eid]; }
    else          { src = dst = eid - E_; }
    float e = asrc[src] + adst[dst];
    e = e > 0.f ? e : LEAKY * e;
    atomicMaxFloat(&m[dst], e);
}

__global__ __launch_bounds__(256) void edge_accum2(const int* __restrict__ ei, int E_, int N_,
                                                   const float* __restrict__ asrc,
                                                   const float* __restrict__ adst,
                                                   const float* __restrict__ m,
                                                   float* __restrict__ den,
                                                   const float* __restrict__ g,
                                                   float* __restrict__ acc) {
    int wave = threadIdx.x >> 6;
    int lane = threadIdx.x & 63;
    int eid = blockIdx.x * 4 + wave;
    int Etot = E_ + N_;
    if (eid >= Etot) return;
    int src, dst;
    if (eid < E_) { src = ei[eid]; dst = ei[E_ + eid]; }
    else          { src = dst = eid - E_; }
    float e = asrc[src] + adst[dst];
    e = e > 0.f ? e : LEAKY * e;
    float w = __expf(e - m[dst]);
    if (lane == 0) atomicAdd(&den[dst], w);
    atomicAdd(&acc[dst * 64 + lane], w * g[src * 64 + lane]);
}

// ---------------- finalize: out = elu(acc/den + bias) (in-place OK) ----------------
__global__ __launch_bounds__(256) void finalize(const float* __restrict__ acc,
                                                const float* __restrict__ den,
                                                const float* __restrict__ bias,
                                                int nN, int HC,
                                                float* __restrict__ outp) {
    int idx = blockIdx.x * 256 + threadIdx.x;
    if (idx >= nN * HC) return;
    int n = idx / HC;
    int c = idx - n * HC;
    int head = c >> 6;
    float v = acc[idx] / (den[n * (HC >> 6) + head] + 1e-16f) + bias[c];
    v = v > 0.f ? v : expm1f(v);
    outp[idx] = v;
}

extern "C" void kernel_launch(void* const* d_in, const int* in_sizes, int n_in,
                              void* d_out, int out_size, void* d_ws, size_t ws_size,
                              hipStream_t stream) {
    const float* x        = (const float*)d_in[0];
    const int*   ei       = (const int*)d_in[1];     // int32 (harness: integer -> const int*)
    // d_in[2] = edge_attr (unused by PyG GATConv with edge_dim=None)
    const float* W1       = (const float*)d_in[3];
    const float* att_src1 = (const float*)d_in[4];
    const float* att_dst1 = (const float*)d_in[5];
    const float* b1       = (const float*)d_in[6];
    const float* W2       = (const float*)d_in[7];
    const float* att_src2 = (const float*)d_in[8];
    const float* att_dst2 = (const float*)d_in[9];
    const float* b2       = (const float*)d_in[10];
    float* out = (float*)d_out;

    const int N = in_sizes[0] / 128;     // 50000
    const int E = in_sizes[1] / 2;       // 800000
    const int Etot = E + N;

    float* ws    = (float*)d_ws;
    float* h1    = ws;                         // N*256  (layer-1 GEMM out; dead after edge_accum1)
    float* h2    = h1 + (size_t)N * 256;       // N*256  (acc1 -> ELU'd in place = layer-2 input)
    float* g2    = h1;                         // N*64   (aliases h1 — h1 dead by then)
    float* asrc1 = h2 + (size_t)N * 256;       // N*4
    float* adst1 = asrc1 + (size_t)N * 4;      // N*4
    float* m1    = adst1 + (size_t)N * 4;      // N*4
    float* den1  = m1 + (size_t)N * 4;         // N*4
    float* asrc2 = den1 + (size_t)N * 4;       // N
    float* adst2 = asrc2 + N;                  // N
    float* m2    = adst2 + N;                  // N
    float* den2  = m2 + N;                     // N

    // ---- init accumulators ----
    hipMemsetAsync(h2,   0, (size_t)N * 256 * sizeof(float), stream);
    hipMemsetAsync(out,  0, (size_t)N * 64 * sizeof(float), stream);
    hipMemsetAsync(den1, 0, (size_t)N * 4 * sizeof(float), stream);
    hipMemsetAsync(den2, 0, (size_t)N * sizeof(float), stream);
    fill_val<<<(N * 4 + 255) / 256, 256, 0, stream>>>(m1, N * 4, -INFINITY);
    fill_val<<<(N + 255) / 256, 256, 0, stream>>>(m2, N, -INFINITY);

    // ---- layer 1 ----
    {
        dim3 g((N + BM - 1) / BM, 256 / BN);
        gemm_f32<<<g, 256, 0, stream>>>(x, W1, h1, N, 128, 256);
    }
    attn_scores<<<(N * 256) / 256, 256, 0, stream>>>(h1, att_src1, att_dst1, asrc1, adst1, N, 256);
    edge_max1<<<(Etot + 255) / 256, 256, 0, stream>>>(ei, E, N, asrc1, adst1, m1);
    edge_accum1<<<(Etot + 3) / 4, 256, 0, stream>>>(ei, E, N, asrc1, adst1, m1, den1, h1, h2);
    finalize<<<((size_t)N * 256 + 255) / 256, 256, 0, stream>>>(h2, den1, b1, N, 256, h2);

    // ---- layer 2 ----
    {
        dim3 g((N + BM - 1) / BM, 64 / BN);
        gemm_f32<<<g, 256, 0, stream>>>(h2, W2, g2, N, 256, 64);
    }
    attn_scores<<<(N * 64) / 256, 256, 0, stream>>>(g2, att_src2, att_dst2, asrc2, adst2, N, 64);
    edge_max2<<<(Etot + 255) / 256, 256, 0, stream>>>(ei, E, N, asrc2, adst2, m2);
    edge_accum2<<<(Etot + 3) / 4, 256, 0, stream>>>(ei, E, N, asrc2, adst2, m2, den2, g2, out);
    finalize<<<((size_t)N * 64 + 255) / 256, 256, 0, stream>>>(out, den2, b2, N, 64, out);
}

// Round 5
// 628.377 us; speedup vs baseline: 2.2443x; 2.2443x over previous
//
#include <hip/hip_runtime.h>
#include <hip/hip_bf16.h>
#include <math.h>

#define LEAKY 0.2f

// ---------------- generic fp32 tiled GEMM: C[M,NC] = A[M,K] @ B[K,NC] ----------------
#define BM 64
#define BN 64
#define BK 32
__global__ __launch_bounds__(256) void gemm_f32(const float* __restrict__ A,
                                                const float* __restrict__ B,
                                                float* __restrict__ C,
                                                int M, int K, int NC) {
    __shared__ float As[BK][BM + 1];
    __shared__ float Bs[BK][BN];
    const int tid = threadIdx.x;
    const int bm = blockIdx.x * BM;
    const int bn = blockIdx.y * BN;
    const int tx = tid & 15, ty = tid >> 4;
    float acc[4][4] = {};
    for (int k0 = 0; k0 < K; k0 += BK) {
        #pragma unroll
        for (int i = 0; i < (BM * BK) / 256; ++i) {
            int idx = tid + i * 256;
            int r = idx >> 5, c = idx & 31;
            int gr = bm + r;
            As[c][r] = (gr < M) ? A[gr * K + k0 + c] : 0.f;
        }
        #pragma unroll
        for (int i = 0; i < (BK * BN) / 256; ++i) {
            int idx = tid + i * 256;
            int r = idx >> 6, c = idx & 63;
            Bs[r][c] = B[(k0 + r) * NC + bn + c];
        }
        __syncthreads();
        #pragma unroll
        for (int k = 0; k < BK; ++k) {
            float a[4], b[4];
            #pragma unroll
            for (int i = 0; i < 4; ++i) a[i] = As[k][ty * 4 + i];
            #pragma unroll
            for (int j = 0; j < 4; ++j) b[j] = Bs[k][tx * 4 + j];
            #pragma unroll
            for (int i = 0; i < 4; ++i)
                #pragma unroll
                for (int j = 0; j < 4; ++j)
                    acc[i][j] += a[i] * b[j];
        }
        __syncthreads();
    }
    #pragma unroll
    for (int i = 0; i < 4; ++i) {
        int gr = bm + ty * 4 + i;
        if (gr < M) {
            #pragma unroll
            for (int j = 0; j < 4; ++j)
                C[gr * NC + bn + tx * 4 + j] = acc[i][j];
        }
    }
}

// ---------------- attention scores ----------------
__global__ __launch_bounds__(256) void attn_scores(const float* __restrict__ h,
                                                   const float* __restrict__ att_s,
                                                   const float* __restrict__ att_d,
                                                   float* __restrict__ asrc,
                                                   float* __restrict__ adst,
                                                   int nN, int HC) {
    int idx = blockIdx.x * 256 + threadIdx.x;
    int lane = threadIdx.x & 63;
    int n = idx / HC;
    int w = idx - n * HC;            // = head*64 + lane
    if (n >= nN) return;
    float hv = h[(size_t)n * HC + w];
    float vs = hv * att_s[w];
    float vd = hv * att_d[w];
    #pragma unroll
    for (int off = 32; off > 0; off >>= 1) {
        vs += __shfl_down(vs, off);
        vd += __shfl_down(vd, off);
    }
    if (lane == 0) {
        int head = w >> 6;
        int H = HC >> 6;
        asrc[n * H + head] = vs;
        adst[n * H + head] = vd;
    }
}

// ---------------- CSR build ----------------
__global__ __launch_bounds__(256) void count_deg(const int* __restrict__ ei, int E_, int N_,
                                                 int* __restrict__ deg) {
    int eid = blockIdx.x * 256 + threadIdx.x;
    int Etot = E_ + N_;
    if (eid >= Etot) return;
    int dst = (eid < E_) ? ei[E_ + eid] : (eid - E_);
    atomicAdd(&deg[dst], 1);
}

// single block, 1024 threads: off = exclusive_scan(deg), off[n] = total
__global__ __launch_bounds__(1024) void scan_offsets(const int* __restrict__ deg,
                                                     int* __restrict__ off, int n) {
    __shared__ int wsum[16];
    int tid = threadIdx.x;
    int lane = tid & 63, w = tid >> 6;
    int chunk = (n + 1023) / 1024;
    int b = tid * chunk;
    int e = min(b + chunk, n);
    int s = 0;
    for (int i = b; i < e; ++i) s += deg[i];
    int v = s;
    #pragma unroll
    for (int o = 1; o < 64; o <<= 1) {
        int t = __shfl_up(v, o);
        if (lane >= o) v += t;
    }
    if (lane == 63) wsum[w] = v;
    __syncthreads();
    if (w == 0) {
        int t = (lane < 16) ? wsum[lane] : 0;
        #pragma unroll
        for (int o = 1; o < 16; o <<= 1) {
            int u = __shfl_up(t, o);
            if (lane >= o) t += u;
        }
        if (lane < 16) wsum[lane] = t;
    }
    __syncthreads();
    int acc = (w > 0 ? wsum[w - 1] : 0) + (v - s);   // exclusive prefix for this thread
    for (int i = b; i < e; ++i) { off[i] = acc; acc += deg[i]; }
    if (e == n) off[n] = acc;   // all tail threads write the same total
}

// scatter src ids into buckets; uses off[] as in-place cursor.
// post: off[d] = end of bucket d (start = off[d-1], or 0 for d==0)
__global__ __launch_bounds__(256) void scatter_edges(const int* __restrict__ ei, int E_, int N_,
                                                     int* __restrict__ off,
                                                     int* __restrict__ csr) {
    int eid = blockIdx.x * 256 + threadIdx.x;
    int Etot = E_ + N_;
    if (eid >= Etot) return;
    int src, dst;
    if (eid < E_) { src = ei[eid]; dst = ei[E_ + eid]; }
    else          { src = dst = eid - E_; }
    int pos = atomicAdd(&off[dst], 1);
    csr[pos] = src;
}

// ---------------- fused GAT aggregation, 4 heads x 64 ch (wave per node) ----------------
__global__ __launch_bounds__(256) void gat_agg_h4(const int* __restrict__ off,
                                                  const int* __restrict__ csr,
                                                  const float* __restrict__ asrc,
                                                  const float* __restrict__ adst,
                                                  const float* __restrict__ hsrc,
                                                  const float* __restrict__ bias,
                                                  float* __restrict__ outp, int N_) {
    int wv = threadIdx.x >> 6, lane = threadIdx.x & 63;
    int node = blockIdx.x * 4 + wv;
    if (node >= N_) return;
    int s = node ? off[node - 1] : 0;
    int e = off[node];
    float4 ad = *(const float4*)(adst + node * 4);
    // pass 1: segment max (lane-parallel over edges)
    float m0 = -INFINITY, m1 = -INFINITY, m2 = -INFINITY, m3 = -INFINITY;
    for (int i = s + lane; i < e; i += 64) {
        int u = csr[i];
        float4 as = *(const float4*)(asrc + u * 4);
        float e0 = as.x + ad.x; e0 = e0 > 0.f ? e0 : LEAKY * e0; m0 = fmaxf(m0, e0);
        float e1 = as.y + ad.y; e1 = e1 > 0.f ? e1 : LEAKY * e1; m1 = fmaxf(m1, e1);
        float e2 = as.z + ad.z; e2 = e2 > 0.f ? e2 : LEAKY * e2; m2 = fmaxf(m2, e2);
        float e3 = as.w + ad.w; e3 = e3 > 0.f ? e3 : LEAKY * e3; m3 = fmaxf(m3, e3);
    }
    #pragma unroll
    for (int o = 32; o > 0; o >>= 1) {
        m0 = fmaxf(m0, __shfl_xor(m0, o));
        m1 = fmaxf(m1, __shfl_xor(m1, o));
        m2 = fmaxf(m2, __shfl_xor(m2, o));
        m3 = fmaxf(m3, __shfl_xor(m3, o));
    }
    // pass 2: weighted accumulate (lanes over channels; every lane redoes the scalar w)
    float a0 = 0.f, a1 = 0.f, a2 = 0.f, a3 = 0.f;
    float d0 = 0.f, d1 = 0.f, d2 = 0.f, d3 = 0.f;
    for (int i = s; i < e; ++i) {
        int u = csr[i];
        float4 as = *(const float4*)(asrc + u * 4);
        float e0 = as.x + ad.x; e0 = e0 > 0.f ? e0 : LEAKY * e0; float w0 = __expf(e0 - m0);
        float e1 = as.y + ad.y; e1 = e1 > 0.f ? e1 : LEAKY * e1; float w1 = __expf(e1 - m1);
        float e2 = as.z + ad.z; e2 = e2 > 0.f ? e2 : LEAKY * e2; float w2 = __expf(e2 - m2);
        float e3 = as.w + ad.w; e3 = e3 > 0.f ? e3 : LEAKY * e3; float w3 = __expf(e3 - m3);
        d0 += w0; d1 += w1; d2 += w2; d3 += w3;
        const float* hp = hsrc + (size_t)u * 256 + lane;
        a0 += w0 * hp[0];
        a1 += w1 * hp[64];
        a2 += w2 * hp[128];
        a3 += w3 * hp[192];
    }
    size_t ob = (size_t)node * 256 + lane;
    float v;
    v = a0 / (d0 + 1e-16f) + bias[lane];       outp[ob]       = v > 0.f ? v : expm1f(v);
    v = a1 / (d1 + 1e-16f) + bias[lane + 64];  outp[ob + 64]  = v > 0.f ? v : expm1f(v);
    v = a2 / (d2 + 1e-16f) + bias[lane + 128]; outp[ob + 128] = v > 0.f ? v : expm1f(v);
    v = a3 / (d3 + 1e-16f) + bias[lane + 192]; outp[ob + 192] = v > 0.f ? v : expm1f(v);
}

// ---------------- fused GAT aggregation, 1 head x 64 ch (wave per node) ----------------
__global__ __launch_bounds__(256) void gat_agg_h1(const int* __restrict__ off,
                                                  const int* __restrict__ csr,
                                                  const float* __restrict__ asrc,
                                                  const float* __restrict__ adst,
                                                  const float* __restrict__ g,
                                                  const float* __restrict__ bias,
                                                  float* __restrict__ outp, int N_) {
    int wv = threadIdx.x >> 6, lane = threadIdx.x & 63;
    int node = blockIdx.x * 4 + wv;
    if (node >= N_) return;
    int s = node ? off[node - 1] : 0;
    int e = off[node];
    float ad = adst[node];
    float mm = -INFINITY;
    for (int i = s + lane; i < e; i += 64) {
        float ev = asrc[csr[i]] + ad;
        ev = ev > 0.f ? ev : LEAKY * ev;
        mm = fmaxf(mm, ev);
    }
    #pragma unroll
    for (int o = 32; o > 0; o >>= 1) mm = fmaxf(mm, __shfl_xor(mm, o));
    float a = 0.f, d = 0.f;
    for (int i = s; i < e; ++i) {
        int u = csr[i];
        float ev = asrc[u] + ad;
        ev = ev > 0.f ? ev : LEAKY * ev;
        float w = __expf(ev - mm);
        d += w;
        a += w * g[(size_t)u * 64 + lane];
    }
    float v = a / (d + 1e-16f) + bias[lane];
    outp[(size_t)node * 64 + lane] = v > 0.f ? v : expm1f(v);
}

extern "C" void kernel_launch(void* const* d_in, const int* in_sizes, int n_in,
                              void* d_out, int out_size, void* d_ws, size_t ws_size,
                              hipStream_t stream) {
    const float* x        = (const float*)d_in[0];
    const int*   ei       = (const int*)d_in[1];     // int32 (harness: integer -> const int*)
    // d_in[2] = edge_attr (unused: PyG GATConv with edge_dim=None)
    const float* W1       = (const float*)d_in[3];
    const float* att_src1 = (const float*)d_in[4];
    const float* att_dst1 = (const float*)d_in[5];
    const float* b1       = (const float*)d_in[6];
    const float* W2       = (const float*)d_in[7];
    const float* att_src2 = (const float*)d_in[8];
    const float* att_dst2 = (const float*)d_in[9];
    const float* b2       = (const float*)d_in[10];
    float* out = (float*)d_out;

    const int N = in_sizes[0] / 128;     // 50000
    const int E = in_sizes[1] / 2;       // 800000
    const int Etot = E + N;

    float* ws    = (float*)d_ws;
    float* h1    = ws;                         // N*256  (L1 GEMM out; dead after gat_agg_h4)
    float* h2    = h1 + (size_t)N * 256;       // N*256  (L1 out = L2 GEMM in)
    float* g2    = h1;                         // N*64   (aliases h1 — dead by then)
    float* asrc1 = h2 + (size_t)N * 256;       // N*4
    float* adst1 = asrc1 + (size_t)N * 4;      // N*4
    float* asrc2 = adst1 + (size_t)N * 4;      // N
    float* adst2 = asrc2 + N;                  // N
    int*   deg   = (int*)(adst2 + N);          // N+1
    int*   off   = deg + (N + 1);              // N+1 (scan out; scatter cursor; bucket ends)
    int*   csr   = off + (N + 1);              // Etot

    // ---- CSR build (graph identical for both layers) ----
    hipMemsetAsync(deg, 0, (N + 1) * sizeof(int), stream);
    count_deg<<<(Etot + 255) / 256, 256, 0, stream>>>(ei, E, N, deg);
    scan_offsets<<<1, 1024, 0, stream>>>(deg, off, N);
    scatter_edges<<<(Etot + 255) / 256, 256, 0, stream>>>(ei, E, N, off, csr);

    // ---- layer 1 ----
    {
        dim3 g((N + BM - 1) / BM, 256 / BN);
        gemm_f32<<<g, 256, 0, stream>>>(x, W1, h1, N, 128, 256);
    }
    attn_scores<<<(N * 256) / 256, 256, 0, stream>>>(h1, att_src1, att_dst1, asrc1, adst1, N, 256);
    gat_agg_h4<<<(N + 3) / 4, 256, 0, stream>>>(off, csr, asrc1, adst1, h1, b1, h2, N);

    // ---- layer 2 ----
    {
        dim3 g((N + BM - 1) / BM, 64 / BN);
        gemm_f32<<<g, 256, 0, stream>>>(h2, W2, g2, N, 256, 64);
    }
    attn_scores<<<(N * 64) / 256, 256, 0, stream>>>(g2, att_src2, att_dst2, asrc2, adst2, N, 64);
    gat_agg_h1<<<(N + 3) / 4, 256, 0, stream>>>(off, csr, asrc2, adst2, g2, b2, out, N);
}